// Round 2
// baseline (31.709 us; speedup 1.0000x reference)
//
#include <hip/hip_runtime.h>

#define BLOCK 256

// R = Rz(az) * Rx(ax) * Ry(ay)  (pytorch3d ZXY convention), columns scaled by
// half-sizes; corner[k] = center + s0*u + s1*v + s2*w with CORNER_SIGNS bits.
__device__ __forceinline__ void make_corners(const float* __restrict__ b, float c[24]) {
    const float px = b[0], py = b[1], pz = b[2];
    const float hx = 0.5f * b[3], hy = 0.5f * b[4], hz = 0.5f * b[5];
    const float az = b[6], ax = b[7], ay = b[8];
    float sz, cz, sx, cx, sy, cy;
    // fast native trig: |angle| <= ~5.5 (normal samples), error ~1e-6,
    // threshold is 9.25e-2 -> safe by ~4 orders of magnitude
    __sincosf(az, &sz, &cz);
    __sincosf(ax, &sx, &cx);
    __sincosf(ay, &sy, &cy);
    // columns of R:
    // col0 = [cz*cy - sz*sx*sy, sz*cy + cz*sx*sy, -cx*sy]
    // col1 = [-sz*cx,           cz*cx,             sx   ]
    // col2 = [cz*sy + sz*sx*cy, sz*sy - cz*sx*cy,  cx*cy]
    const float u0 = hx * (cz * cy - sz * sx * sy);
    const float u1 = hx * (sz * cy + cz * sx * sy);
    const float u2 = hx * (-cx * sy);
    const float v0 = hy * (-sz * cx);
    const float v1 = hy * (cz * cx);
    const float v2 = hy * (sx);
    const float w0 = hz * (cz * sy + sz * sx * cy);
    const float w1 = hz * (sz * sy - cz * sx * cy);
    const float w2 = hz * (cx * cy);
#pragma unroll
    for (int k = 0; k < 8; ++k) {
        const float s0 = (k & 4) ? -1.f : 1.f;
        const float s1 = (k & 2) ? -1.f : 1.f;
        const float s2 = (k & 1) ? -1.f : 1.f;
        c[k * 3 + 0] = px + s0 * u0 + s1 * v0 + s2 * w0;
        c[k * 3 + 1] = py + s0 * u1 + s1 * v1 + s2 * w1;
        c[k * 3 + 2] = pz + s0 * u2 + s1 * v2 + s2 * w2;
    }
}

__global__ __launch_bounds__(BLOCK) void bbox_cd_fused(
    const float* __restrict__ src, const float* __restrict__ tgt,
    unsigned int* __restrict__ counter, float* __restrict__ partials,
    float* __restrict__ out, int n, float inv_count) {
    __shared__ float s_src[BLOCK * 9];
    __shared__ float s_tgt[BLOCK * 9];

    const int block_base = blockIdx.x * BLOCK;
    const int nb = min(BLOCK, n - block_base);
    const int total = nb * 9;

    // coalesced staging: contiguous 9*nb floats per array.
    // LDS read pattern s_src[9t+k]: 9 coprime with 32 -> 2 lanes/bank (free).
    for (int i = threadIdx.x; i < total; i += BLOCK) {
        s_src[i] = src[block_base * 9 + i];
        s_tgt[i] = tgt[block_base * 9 + i];
    }
    __syncthreads();

    float lsum = 0.f;
    const int t = threadIdx.x;
    if (t < nb) {
        float sc[24], tc[24];
        make_corners(&s_src[t * 9], sc);
        make_corners(&s_tgt[t * 9], tc);
        float sum = 0.f;
#pragma unroll
        for (int i = 0; i < 8; ++i) {
            const float ax = sc[i * 3 + 0];
            const float ay = sc[i * 3 + 1];
            const float az = sc[i * 3 + 2];
            float best = 3.4e38f;
#pragma unroll
            for (int j = 0; j < 8; ++j) {
                const float dx = ax - tc[j * 3 + 0];
                const float dy = ay - tc[j * 3 + 1];
                const float dz = az - tc[j * 3 + 2];
                const float d = fmaf(dz, dz, fmaf(dy, dy, dx * dx));
                best = fminf(best, d);
            }
            sum += best;
        }
        lsum = sum;
    }

    // wave (64-lane) shuffle reduction, then cross-wave via LDS
#pragma unroll
    for (int off = 32; off > 0; off >>= 1) lsum += __shfl_down(lsum, off, 64);

    __shared__ float wsum[BLOCK / 64];
    __shared__ int is_last;
    const int wave = threadIdx.x >> 6;
    const int lane = threadIdx.x & 63;
    if (lane == 0) wsum[wave] = lsum;
    __syncthreads();
    if (threadIdx.x == 0) {
        float b = 0.f;
#pragma unroll
        for (int w = 0; w < BLOCK / 64; ++w) b += wsum[w];
        // publish partial (agent scope), then release-increment the counter
        __hip_atomic_store(&partials[blockIdx.x], b, __ATOMIC_RELAXED,
                           __HIP_MEMORY_SCOPE_AGENT);
        unsigned int old = __hip_atomic_fetch_add(counter, 1u, __ATOMIC_ACQ_REL,
                                                  __HIP_MEMORY_SCOPE_AGENT);
        is_last = (old == gridDim.x - 1) ? 1 : 0;
    }
    __syncthreads();

    // last-arriving block reduces all partials in FIXED index order ->
    // bitwise-deterministic result independent of arrival order.
    if (is_last) {
        float s = 0.f;
        for (int i = threadIdx.x; i < (int)gridDim.x; i += BLOCK)
            s += __hip_atomic_load(&partials[i], __ATOMIC_RELAXED,
                                   __HIP_MEMORY_SCOPE_AGENT);
#pragma unroll
        for (int off = 32; off > 0; off >>= 1) s += __shfl_down(s, off, 64);
        if (lane == 0) wsum[wave] = s;
        __syncthreads();
        if (threadIdx.x == 0) {
            float b = 0.f;
#pragma unroll
            for (int w = 0; w < BLOCK / 64; ++w) b += wsum[w];
            out[0] = b * inv_count;
        }
    }
}

extern "C" void kernel_launch(void* const* d_in, const int* in_sizes, int n_in,
                              void* d_out, int out_size, void* d_ws, size_t ws_size,
                              hipStream_t stream) {
    const float* src = (const float*)d_in[0];
    const float* tgt = (const float*)d_in[1];
    float* out = (float*)d_out;
    const int n = in_sizes[0] / 9;  // 262144
    const int nblocks = (n + BLOCK - 1) / BLOCK;

    // ws layout: [0..3] counter, [16 ..) partials (nblocks floats)
    unsigned int* counter = (unsigned int*)d_ws;
    float* partials = (float*)((char*)d_ws + 16);

    // counter must start at 0 every call (ws is poisoned once, never restored)
    hipMemsetAsync(d_ws, 0, 4, stream);

    const float inv_count = 1.0f / (float)((long long)n * 8);
    bbox_cd_fused<<<nblocks, BLOCK, 0, stream>>>(src, tgt, counter, partials,
                                                 out, n, inv_count);
}

// Round 4
// 12.260 us; speedup vs baseline: 2.5865x; 2.5865x over previous
//
#include <hip/hip_runtime.h>

#define BLOCK 256

// Build center p and half-size-scaled rotation columns u,v,w for one box.
// R = Rz(az)*Rx(ax)*Ry(ay) (pytorch3d ZXY); corner_k = p + s0*u + s1*v + s2*w.
__device__ __forceinline__ void make_frame(const float* __restrict__ b,
                                           float p[3], float u[3], float v[3],
                                           float w[3]) {
    p[0] = b[0]; p[1] = b[1]; p[2] = b[2];
    const float hx = 0.5f * b[3], hy = 0.5f * b[4], hz = 0.5f * b[5];
    const float az = b[6], ax = b[7], ay = b[8];
    float sz, cz, sx, cx, sy, cy;
    // native trig: |angle| <= ~5.5 for N(0,1) inputs; err ~1e-6 << 9.25e-2
    __sincosf(az, &sz, &cz);
    __sincosf(ax, &sx, &cx);
    __sincosf(ay, &sy, &cy);
    u[0] = hx * (cz * cy - sz * sx * sy);
    u[1] = hx * (sz * cy + cz * sx * sy);
    u[2] = hx * (-cx * sy);
    v[0] = hy * (-sz * cx);
    v[1] = hy * (cz * cx);
    v[2] = hy * (sx);
    w[0] = hz * (cz * sy + sz * sx * cy);
    w[1] = hz * (sz * sy - cz * sx * cy);
    w[2] = hz * (cx * cy);
}

__global__ __launch_bounds__(BLOCK) void bbox_cd_partial(
    const float* __restrict__ src, const float* __restrict__ tgt,
    float* __restrict__ partial, int n) {
    __shared__ float s_src[BLOCK * 9];
    __shared__ float s_tgt[BLOCK * 9];

    const int block_base = blockIdx.x * BLOCK;
    const int nb = min(BLOCK, n - block_base);

    if (nb == BLOCK) {
        const float4* s4 = reinterpret_cast<const float4*>(src + (size_t)block_base * 9);
        const float4* t4 = reinterpret_cast<const float4*>(tgt + (size_t)block_base * 9);
        float4* ds = reinterpret_cast<float4*>(s_src);
        float4* dt = reinterpret_cast<float4*>(s_tgt);
#pragma unroll
        for (int i = threadIdx.x; i < (BLOCK * 9) / 4; i += BLOCK) {
            ds[i] = s4[i];
            dt[i] = t4[i];
        }
    } else {
        for (int i = threadIdx.x; i < nb * 9; i += BLOCK) {
            s_src[i] = src[(size_t)block_base * 9 + i];
            s_tgt[i] = tgt[(size_t)block_base * 9 + i];
        }
    }
    __syncthreads();

    float lsum = 0.f;
    const int t = threadIdx.x;
    if (t < nb) {
        float ps[3], us[3], vs[3], ws_[3];
        float pt[3], ut[3], vt[3], wt[3];
        make_frame(&s_src[t * 9], ps, us, vs, ws_);
        make_frame(&s_tgt[t * 9], pt, ut, vt, wt);

        // d = center delta; antipodal-pair algebra:
        //   source corners: q± = d ± c_i, i0=0..3 (c = u + s1 v + s2 w)
        //   target corners: ±r_j, j=0..3
        //   min(dist(q, r), dist(q, -r)) = |q|^2 + |r|^2 - |2 q·r|
        //   and sum over the ±c pair cancels the 2 d·c term:
        //   loss(+c)+loss(-c) = 2(|d|^2+|c|^2) + bestP + bestM
        const float d0 = ps[0] - pt[0];
        const float d1 = ps[1] - pt[1];
        const float d2c = ps[2] - pt[2];
        const float dd = fmaf(d0, d0, fmaf(d1, d1, d2c * d2c));
        const float e0 = d0 + d0, e1 = d1 + d1, e2 = d2c + d2c;  // 2d

        float r[4][3], Rj[4], Gj[4];
#pragma unroll
        for (int j = 0; j < 4; ++j) {
            const float s1 = (j & 2) ? -1.f : 1.f;
            const float s2 = (j & 1) ? -1.f : 1.f;
#pragma unroll
            for (int k = 0; k < 3; ++k)
                r[j][k] = ut[k] + s1 * vt[k] + s2 * wt[k];
            Rj[j] = fmaf(r[j][0], r[j][0],
                         fmaf(r[j][1], r[j][1], r[j][2] * r[j][2]));
            Gj[j] = fmaf(e0, r[j][0], fmaf(e1, r[j][1], e2 * r[j][2]));  // 2 d·r
        }

        float sum = 0.f;
#pragma unroll
        for (int i = 0; i < 4; ++i) {
            const float s1 = (i & 2) ? -1.f : 1.f;
            const float s2 = (i & 1) ? -1.f : 1.f;
            float c0, c1, c2;
            c0 = us[0] + s1 * vs[0] + s2 * ws_[0];
            c1 = us[1] + s1 * vs[1] + s2 * ws_[1];
            c2 = us[2] + s1 * vs[2] + s2 * ws_[2];
            const float cc = fmaf(c0, c0, fmaf(c1, c1, c2 * c2));
            const float A = dd + cc;
            const float f0 = c0 + c0, f1 = c1 + c1, f2 = c2 + c2;  // 2c
            float bestP = 3.4e38f, bestM = 3.4e38f;
#pragma unroll
            for (int j = 0; j < 4; ++j) {
                const float H = fmaf(f0, r[j][0],
                                     fmaf(f1, r[j][1], f2 * r[j][2]));  // 2 c·r
                const float t1 = Gj[j] + H;   // 2 q+·r
                const float t2 = Gj[j] - H;   // 2 q-·r
                bestP = fminf(bestP, Rj[j] - fabsf(t1));
                bestM = fminf(bestM, Rj[j] - fabsf(t2));
            }
            sum += (A + A) + bestP + bestM;
        }
        lsum = sum;
    }

    // wave (64-lane) shuffle reduction, then cross-wave via LDS
#pragma unroll
    for (int off = 32; off > 0; off >>= 1) lsum += __shfl_down(lsum, off, 64);

    __shared__ float wsum[BLOCK / 64];
    const int wave = threadIdx.x >> 6;
    const int lane = threadIdx.x & 63;
    if (lane == 0) wsum[wave] = lsum;
    __syncthreads();
    if (threadIdx.x == 0) {
        float b = 0.f;
#pragma unroll
        for (int w = 0; w < BLOCK / 64; ++w) b += wsum[w];
        partial[blockIdx.x] = b;
    }
}

__global__ __launch_bounds__(BLOCK) void bbox_cd_final(
    const float* __restrict__ partial, int nblocks, float* __restrict__ out,
    float inv_count) {
    float s = 0.f;
    for (int i = threadIdx.x; i < nblocks; i += BLOCK) s += partial[i];
#pragma unroll
    for (int off = 32; off > 0; off >>= 1) s += __shfl_down(s, off, 64);

    __shared__ float wsum[BLOCK / 64];
    const int wave = threadIdx.x >> 6;
    const int lane = threadIdx.x & 63;
    if (lane == 0) wsum[wave] = s;
    __syncthreads();
    if (threadIdx.x == 0) {
        float b = 0.f;
#pragma unroll
        for (int w = 0; w < BLOCK / 64; ++w) b += wsum[w];
        out[0] = b * inv_count;
    }
}

extern "C" void kernel_launch(void* const* d_in, const int* in_sizes, int n_in,
                              void* d_out, int out_size, void* d_ws, size_t ws_size,
                              hipStream_t stream) {
    const float* src = (const float*)d_in[0];
    const float* tgt = (const float*)d_in[1];
    float* out = (float*)d_out;
    const int n = in_sizes[0] / 9;  // 262144
    const int nblocks = (n + BLOCK - 1) / BLOCK;

    float* partial = (float*)d_ws;

    bbox_cd_partial<<<nblocks, BLOCK, 0, stream>>>(src, tgt, partial, n);
    const float inv_count = 1.0f / (float)((long long)n * 8);
    bbox_cd_final<<<1, BLOCK, 0, stream>>>(partial, nblocks, out, inv_count);
}